// Round 1
// baseline (4335.027 us; speedup 1.0000x reference)
//
#include <hip/hip_runtime.h>
#include <hip/hip_bf16.h>
#include <cstddef>

// ---------------------------------------------------------------------------
// Problem: 3-layer MPNN, N=50000 nodes, E=800000 edges, D_IN=H=128, OUT=32.
//   per layer: m = h@Wm^T ; acc = h@Wu^T + bu ; acc[dst] += w_e * m[src] ;
//              h' = tanh(acc)   (tanh fused into NEXT gemm's A staging)
//   out = tanh-free: out = h3@Wout^T + bout  (h3 = tanh(acc2) fused in staging)
// Workspace layout (floats): mbuf[N*128] | acc0[N*128] | acc1[N*128] | flag
//   = 76.8 MB + 4 B
// ---------------------------------------------------------------------------

#define WS_STRIDE ((size_t)50048 * 128)  // a little headroom per buffer

// Detect whether edge_index was uploaded as int32 or int64.
// int64 little-endian: every odd int32 (high word) of the first entries is 0.
// int32: odd entries are random node ids < 50000, almost surely nonzero.
// flag[0] = 1 -> int32 layout, 0 -> int64 layout.
__global__ void detect_idx_kernel(const int* __restrict__ ei, int* __restrict__ flag, int E) {
    __shared__ int any;
    if (threadIdx.x == 0) any = 0;
    __syncthreads();
    int n = E < 2048 ? E : 2048;
    for (int i = threadIdx.x; i < n; i += 256) {
        if (ei[2 * i + 1] != 0) any = 1;
    }
    __syncthreads();
    if (threadIdx.x == 0) flag[0] = any;
}

// ---------------------------------------------------------------------------
// Tiled fp32 GEMM: C[N,128] = op(A)[N,128] @ W[128,128]^T (+ bias)
// op = tanh if TANH_IN. Block 256 threads, BM=64 rows, BK=32.
// Thread (ty,tx): ty=tid>>5 (8 row groups of 8), tx=tid&31 (col groups of 4).
// LDS transposed: AsT[k][row] (stride 68), WsT[k][j] (stride 132) so the
// inner loop uses ds_read_b128 (16B-aligned, conflict-free / broadcast).
// ---------------------------------------------------------------------------
template <bool TANH_IN, bool HAS_BIAS>
__global__ __launch_bounds__(256) void gemm128(
    const float* __restrict__ A, const float* __restrict__ W,
    const float* __restrict__ bias, float* __restrict__ C, int N) {
    __shared__ float AsT[32][68];
    __shared__ float WsT[32][132];
    const int tid = threadIdx.x;
    const int tx = tid & 31, ty = tid >> 5;
    const int row0 = blockIdx.x * 64;

    float acc[8][4];
#pragma unroll
    for (int r = 0; r < 8; ++r)
#pragma unroll
        for (int c = 0; c < 4; ++c) acc[r][c] = 0.f;

    for (int kc = 0; kc < 128; kc += 32) {
        __syncthreads();  // protect LDS reuse across iterations
        // Stage A tile: 64 rows x 32 k = 512 float4, 2 per thread (transposed)
#pragma unroll
        for (int q = 0; q < 2; ++q) {
            int idx = tid + 256 * q;
            int r = idx >> 3, k4 = idx & 7;
            int gr = row0 + r;
            float4 v = make_float4(0.f, 0.f, 0.f, 0.f);
            if (gr < N) v = *(const float4*)(A + (size_t)gr * 128 + kc + k4 * 4);
            if (TANH_IN) { v.x = tanhf(v.x); v.y = tanhf(v.y); v.z = tanhf(v.z); v.w = tanhf(v.w); }
            AsT[k4 * 4 + 0][r] = v.x;
            AsT[k4 * 4 + 1][r] = v.y;
            AsT[k4 * 4 + 2][r] = v.z;
            AsT[k4 * 4 + 3][r] = v.w;
        }
        // Stage W tile: 128 j x 32 k = 1024 float4, 4 per thread (transposed)
#pragma unroll
        for (int q = 0; q < 4; ++q) {
            int idx = tid + 256 * q;
            int j = idx >> 3, k4 = idx & 7;
            float4 v = *(const float4*)(W + j * 128 + kc + k4 * 4);
            WsT[k4 * 4 + 0][j] = v.x;
            WsT[k4 * 4 + 1][j] = v.y;
            WsT[k4 * 4 + 2][j] = v.z;
            WsT[k4 * 4 + 3][j] = v.w;
        }
        __syncthreads();
#pragma unroll
        for (int k = 0; k < 32; ++k) {
            float4 a0 = *(const float4*)&AsT[k][ty * 8];
            float4 a1 = *(const float4*)&AsT[k][ty * 8 + 4];
            float4 wv = *(const float4*)&WsT[k][tx * 4];
            float av[8] = {a0.x, a0.y, a0.z, a0.w, a1.x, a1.y, a1.z, a1.w};
#pragma unroll
            for (int r = 0; r < 8; ++r) {
                acc[r][0] += av[r] * wv.x;
                acc[r][1] += av[r] * wv.y;
                acc[r][2] += av[r] * wv.z;
                acc[r][3] += av[r] * wv.w;
            }
        }
    }
    float4 bv = make_float4(0.f, 0.f, 0.f, 0.f);
    if (HAS_BIAS) bv = *(const float4*)(bias + tx * 4);
#pragma unroll
    for (int r = 0; r < 8; ++r) {
        int gr = row0 + ty * 8 + r;
        if (gr >= N) continue;
        float4 v = make_float4(acc[r][0] + bv.x, acc[r][1] + bv.y,
                               acc[r][2] + bv.z, acc[r][3] + bv.w);
        *(float4*)(C + (size_t)gr * 128 + tx * 4) = v;
    }
}

// ---------------------------------------------------------------------------
// Output GEMM: C[N,32] = tanh(A)[N,128] @ W[32,128]^T + bias. BM=32 rows.
// ---------------------------------------------------------------------------
__global__ __launch_bounds__(256) void gemm_out(
    const float* __restrict__ A, const float* __restrict__ W,
    const float* __restrict__ bias, float* __restrict__ C, int N) {
    __shared__ float AsT[128][36];
    __shared__ float WT[128][36];
    const int tid = threadIdx.x;
    const int row0 = blockIdx.x * 32;
    // Stage A: 32 rows x 128 k = 1024 float4, 4/thread, tanh applied
#pragma unroll
    for (int q = 0; q < 4; ++q) {
        int idx = tid + 256 * q;
        int r = idx >> 5, k4 = idx & 31;
        int gr = row0 + r;
        float4 v = make_float4(0.f, 0.f, 0.f, 0.f);
        if (gr < N) v = *(const float4*)(A + (size_t)gr * 128 + k4 * 4);
        v.x = tanhf(v.x); v.y = tanhf(v.y); v.z = tanhf(v.z); v.w = tanhf(v.w);
        AsT[k4 * 4 + 0][r] = v.x;
        AsT[k4 * 4 + 1][r] = v.y;
        AsT[k4 * 4 + 2][r] = v.z;
        AsT[k4 * 4 + 3][r] = v.w;
    }
    // Stage W: 32 j x 128 k = 1024 float4, 4/thread (transposed)
#pragma unroll
    for (int q = 0; q < 4; ++q) {
        int idx = tid + 256 * q;
        int j = idx >> 5, k4 = idx & 31;
        float4 v = *(const float4*)(W + j * 128 + k4 * 4);
        WT[k4 * 4 + 0][j] = v.x;
        WT[k4 * 4 + 1][j] = v.y;
        WT[k4 * 4 + 2][j] = v.z;
        WT[k4 * 4 + 3][j] = v.w;
    }
    __syncthreads();
    const int tx = tid & 31, ty = tid >> 5;  // tx = output col, ty*4.. rows
    float acc[4] = {0.f, 0.f, 0.f, 0.f};
#pragma unroll 4
    for (int k = 0; k < 128; ++k) {
        float w = WT[k][tx];
        float4 a = *(const float4*)&AsT[k][ty * 4];
        acc[0] += a.x * w;
        acc[1] += a.y * w;
        acc[2] += a.z * w;
        acc[3] += a.w * w;
    }
    float b = bias[tx];
#pragma unroll
    for (int r = 0; r < 4; ++r) {
        int gr = row0 + ty * 4 + r;
        if (gr < N) C[(size_t)gr * 32 + tx] = acc[r] + b;
    }
}

// ---------------------------------------------------------------------------
// Edge scatter: acc[dst] += w * m[src]. 32 lanes per edge, float4 gather,
// 4 scalar fp32 atomics. Handles int32 / int64 edge_index via runtime flag.
// ---------------------------------------------------------------------------
__global__ __launch_bounds__(256) void edge_scatter(
    const int* __restrict__ ei, const float* __restrict__ ew,
    const float* __restrict__ m, float* __restrict__ acc, int E,
    const int* __restrict__ flag) {
    int t = blockIdx.x * 256 + threadIdx.x;
    int e = t >> 5;
    if (e >= E) return;
    int f = (t & 31) << 2;
    int s, d;
    if (flag[0]) {  // int32 layout: [src[E] | dst[E]]
        s = ei[e];
        d = ei[E + e];
    } else {  // int64 layout: low words at even int32 offsets
        s = ei[2 * e];
        d = ei[2 * ((size_t)E + e)];
    }
    float w = ew[e];
    const float4 v = *(const float4*)(m + (size_t)s * 128 + f);
    float* ap = acc + (size_t)d * 128 + f;
    atomicAdd(ap + 0, w * v.x);
    atomicAdd(ap + 1, w * v.y);
    atomicAdd(ap + 2, w * v.z);
    atomicAdd(ap + 3, w * v.w);
}

extern "C" void kernel_launch(void* const* d_in, const int* in_sizes, int n_in,
                              void* d_out, int out_size, void* d_ws, size_t ws_size,
                              hipStream_t stream) {
    const float* x   = (const float*)d_in[0];
    const int* ei    = (const int*)d_in[1];
    const float* ew  = (const float*)d_in[2];
    const float* Wm[3] = {(const float*)d_in[3], (const float*)d_in[6], (const float*)d_in[9]};
    const float* Wu[3] = {(const float*)d_in[4], (const float*)d_in[7], (const float*)d_in[10]};
    const float* bu[3] = {(const float*)d_in[5], (const float*)d_in[8], (const float*)d_in[11]};
    const float* Wout = (const float*)d_in[12];
    const float* bout = (const float*)d_in[13];
    float* out = (float*)d_out;

    const int N = in_sizes[0] / 128;
    const int E = in_sizes[2];

    float* ws   = (float*)d_ws;
    float* mbuf = ws;
    float* acc0 = ws + WS_STRIDE;
    float* acc1 = ws + 2 * WS_STRIDE;
    int* flag   = (int*)(ws + 3 * WS_STRIDE);

    detect_idx_kernel<<<1, 256, 0, stream>>>(ei, flag, E);

    const int gG = (N + 63) / 64;
    const int gE = (int)(((long long)E * 32 + 255) / 256);
    const int gO = (N + 31) / 32;

    // Layer 0: input = x (no tanh)
    gemm128<false, false><<<gG, 256, 0, stream>>>(x, Wm[0], nullptr, mbuf, N);
    gemm128<false, true><<<gG, 256, 0, stream>>>(x, Wu[0], bu[0], acc0, N);
    edge_scatter<<<gE, 256, 0, stream>>>(ei, ew, mbuf, acc0, E, flag);

    // Layer 1: input = tanh(acc0)
    gemm128<true, false><<<gG, 256, 0, stream>>>(acc0, Wm[1], nullptr, mbuf, N);
    gemm128<true, true><<<gG, 256, 0, stream>>>(acc0, Wu[1], bu[1], acc1, N);
    edge_scatter<<<gE, 256, 0, stream>>>(ei, ew, mbuf, acc1, E, flag);

    // Layer 2: input = tanh(acc1)
    gemm128<true, false><<<gG, 256, 0, stream>>>(acc1, Wm[2], nullptr, mbuf, N);
    gemm128<true, true><<<gG, 256, 0, stream>>>(acc1, Wu[2], bu[2], acc0, N);
    edge_scatter<<<gE, 256, 0, stream>>>(ei, ew, mbuf, acc0, E, flag);

    // Output: out = tanh(acc0) @ Wout^T + bout
    gemm_out<<<gO, 256, 0, stream>>>(acc0, Wout, bout, out, N);
}

// Round 2
// 686.871 us; speedup vs baseline: 6.3113x; 6.3113x over previous
//
#include <hip/hip_runtime.h>
#include <hip/hip_bf16.h>
#include <cstddef>

// ---------------------------------------------------------------------------
// 3-layer MPNN, N=50000, E=800000, D=128, OUT=32.
// R2: scatter-add via fp32 global atomics was the bottleneck (1.6 GB of
// write-through atomic traffic per layer, ~76 G atomics/s ceiling).
// Replace with device-built CSR (by dst) + gather-based aggregation:
// zero fp32 atomics, exact writes (25.6 MB/layer).
// Workspace: mbuf | acc0 | acc1 (floats) | flag | deg[N] | rowptr[N] |
//            csr_src[E] | csr_w[E]
// ---------------------------------------------------------------------------

#define WS_STRIDE ((size_t)50048 * 128)

// flag[0] = 1 -> edge_index stored as int32 [2][E]; 0 -> int64 [2][E].
__global__ void detect_idx_kernel(const int* __restrict__ ei, int* __restrict__ flag, int E) {
    __shared__ int any;
    if (threadIdx.x == 0) any = 0;
    __syncthreads();
    int n = E < 2048 ? E : 2048;
    for (int i = threadIdx.x; i < n; i += 256) {
        if (ei[2 * i + 1] != 0) any = 1;
    }
    __syncthreads();
    if (threadIdx.x == 0) flag[0] = any;
}

__device__ inline void get_edge(const int* __restrict__ ei, int e, int E, int f,
                                int& s, int& d) {
    if (f) {            // int32: [src[E] | dst[E]]
        s = ei[e];
        d = ei[E + e];
    } else {            // int64 little-endian: low words at even offsets
        s = ei[2 * (size_t)e];
        d = ei[2 * ((size_t)E + e)];
    }
}

__global__ __launch_bounds__(256) void zero_kernel(int* __restrict__ p, int n) {
    int i = blockIdx.x * 256 + threadIdx.x;
    if (i < n) p[i] = 0;
}

__global__ __launch_bounds__(256) void hist_kernel(
    const int* __restrict__ ei, int* __restrict__ deg, int E,
    const int* __restrict__ flag) {
    int e = blockIdx.x * 256 + threadIdx.x;
    if (e >= E) return;
    int s, d;
    get_edge(ei, e, E, flag[0], s, d);
    atomicAdd(&deg[d], 1);
}

// Single-block exclusive scan: rowptr[i] = sum(deg[0..i-1]).
__global__ __launch_bounds__(256) void scan_kernel(
    const int* __restrict__ deg, int* __restrict__ rowptr, int n) {
    __shared__ int sums[256];
    int tid = threadIdx.x;
    int chunk = (n + 255) / 256;
    int beg = tid * chunk;
    int end = beg + chunk < n ? beg + chunk : n;
    int s = 0;
    for (int i = beg; i < end; ++i) s += deg[i];
    sums[tid] = s;
    __syncthreads();
    for (int off = 1; off < 256; off <<= 1) {
        int v = (tid >= off) ? sums[tid - off] : 0;
        __syncthreads();
        sums[tid] += v;
        __syncthreads();
    }
    int run = (tid == 0) ? 0 : sums[tid - 1];
    for (int i = beg; i < end; ++i) {
        rowptr[i] = run;
        run += deg[i];
    }
}

// Bucket-fill; mutates rowptr[d] from start offset to end offset.
__global__ __launch_bounds__(256) void fill_kernel(
    const int* __restrict__ ei, const float* __restrict__ ew,
    int* __restrict__ rowptr, int* __restrict__ csr_src,
    float* __restrict__ csr_w, int E, const int* __restrict__ flag) {
    int e = blockIdx.x * 256 + threadIdx.x;
    if (e >= E) return;
    int s, d;
    get_edge(ei, e, E, flag[0], s, d);
    int pos = atomicAdd(&rowptr[d], 1);
    csr_src[pos] = s;
    csr_w[pos] = ew[e];
}

// ---------------------------------------------------------------------------
// Gather aggregation: acc[d] += sum_{e in in(d)} w_e * m[src_e].
// One 64-lane wave per node; lane owns feature cols {2*lane, 2*lane+1}.
// rowend[d] is the END offset (post-fill rowptr); beg = end - deg[d].
// ---------------------------------------------------------------------------
__global__ __launch_bounds__(256) void aggregate_kernel(
    const int* __restrict__ csr_src, const float* __restrict__ csr_w,
    const int* __restrict__ rowend, const int* __restrict__ deg,
    const float* __restrict__ m, float* __restrict__ acc, int N) {
    int node = (blockIdx.x * 256 + threadIdx.x) >> 6;
    if (node >= N) return;
    int lane = threadIdx.x & 63;
    int end = rowend[node];
    int beg = end - deg[node];
    float sx = 0.f, sy = 0.f;
    int j = beg;
    for (; j + 1 < end; j += 2) {
        int s0 = csr_src[j],     s1 = csr_src[j + 1];
        float w0 = csr_w[j],     w1 = csr_w[j + 1];
        const float2 v0 = *(const float2*)(m + (size_t)s0 * 128 + lane * 2);
        const float2 v1 = *(const float2*)(m + (size_t)s1 * 128 + lane * 2);
        sx += w0 * v0.x + w1 * v1.x;
        sy += w0 * v0.y + w1 * v1.y;
    }
    if (j < end) {
        int s0 = csr_src[j];
        float w0 = csr_w[j];
        const float2 v0 = *(const float2*)(m + (size_t)s0 * 128 + lane * 2);
        sx += w0 * v0.x;
        sy += w0 * v0.y;
    }
    float2* ap = (float2*)(acc + (size_t)node * 128 + lane * 2);
    float2 cur = *ap;  // holds h@Wu^T + bu
    cur.x += sx;
    cur.y += sy;
    *ap = cur;
}

// ---------------------------------------------------------------------------
// Tiled fp32 GEMM: C[N,128] = op(A)[N,128] @ W[128,128]^T (+ bias), op=tanh?
// ---------------------------------------------------------------------------
template <bool TANH_IN, bool HAS_BIAS>
__global__ __launch_bounds__(256) void gemm128(
    const float* __restrict__ A, const float* __restrict__ W,
    const float* __restrict__ bias, float* __restrict__ C, int N) {
    __shared__ float AsT[32][68];
    __shared__ float WsT[32][132];
    const int tid = threadIdx.x;
    const int tx = tid & 31, ty = tid >> 5;
    const int row0 = blockIdx.x * 64;

    float acc[8][4];
#pragma unroll
    for (int r = 0; r < 8; ++r)
#pragma unroll
        for (int c = 0; c < 4; ++c) acc[r][c] = 0.f;

    for (int kc = 0; kc < 128; kc += 32) {
        __syncthreads();
#pragma unroll
        for (int q = 0; q < 2; ++q) {
            int idx = tid + 256 * q;
            int r = idx >> 3, k4 = idx & 7;
            int gr = row0 + r;
            float4 v = make_float4(0.f, 0.f, 0.f, 0.f);
            if (gr < N) v = *(const float4*)(A + (size_t)gr * 128 + kc + k4 * 4);
            if (TANH_IN) { v.x = tanhf(v.x); v.y = tanhf(v.y); v.z = tanhf(v.z); v.w = tanhf(v.w); }
            AsT[k4 * 4 + 0][r] = v.x;
            AsT[k4 * 4 + 1][r] = v.y;
            AsT[k4 * 4 + 2][r] = v.z;
            AsT[k4 * 4 + 3][r] = v.w;
        }
#pragma unroll
        for (int q = 0; q < 4; ++q) {
            int idx = tid + 256 * q;
            int j = idx >> 3, k4 = idx & 7;
            float4 v = *(const float4*)(W + j * 128 + kc + k4 * 4);
            WsT[k4 * 4 + 0][j] = v.x;
            WsT[k4 * 4 + 1][j] = v.y;
            WsT[k4 * 4 + 2][j] = v.z;
            WsT[k4 * 4 + 3][j] = v.w;
        }
        __syncthreads();
#pragma unroll
        for (int k = 0; k < 32; ++k) {
            float4 a0 = *(const float4*)&AsT[k][ty * 8];
            float4 a1 = *(const float4*)&AsT[k][ty * 8 + 4];
            float4 wv = *(const float4*)&WsT[k][tx * 4];
            float av[8] = {a0.x, a0.y, a0.z, a0.w, a1.x, a1.y, a1.z, a1.w};
#pragma unroll
            for (int r = 0; r < 8; ++r) {
                acc[r][0] += av[r] * wv.x;
                acc[r][1] += av[r] * wv.y;
                acc[r][2] += av[r] * wv.z;
                acc[r][3] += av[r] * wv.w;
            }
        }
    }
    float4 bv = make_float4(0.f, 0.f, 0.f, 0.f);
    if (HAS_BIAS) bv = *(const float4*)(bias + tx * 4);
#pragma unroll
    for (int r = 0; r < 8; ++r) {
        int gr = row0 + ty * 8 + r;
        if (gr >= N) continue;
        float4 v = make_float4(acc[r][0] + bv.x, acc[r][1] + bv.y,
                               acc[r][2] + bv.z, acc[r][3] + bv.w);
        *(float4*)(C + (size_t)gr * 128 + tx * 4) = v;
    }
}

// C[N,32] = tanh(A)[N,128] @ W[32,128]^T + bias
__global__ __launch_bounds__(256) void gemm_out(
    const float* __restrict__ A, const float* __restrict__ W,
    const float* __restrict__ bias, float* __restrict__ C, int N) {
    __shared__ float AsT[128][36];
    __shared__ float WT[128][36];
    const int tid = threadIdx.x;
    const int row0 = blockIdx.x * 32;
#pragma unroll
    for (int q = 0; q < 4; ++q) {
        int idx = tid + 256 * q;
        int r = idx >> 5, k4 = idx & 31;
        int gr = row0 + r;
        float4 v = make_float4(0.f, 0.f, 0.f, 0.f);
        if (gr < N) v = *(const float4*)(A + (size_t)gr * 128 + k4 * 4);
        v.x = tanhf(v.x); v.y = tanhf(v.y); v.z = tanhf(v.z); v.w = tanhf(v.w);
        AsT[k4 * 4 + 0][r] = v.x;
        AsT[k4 * 4 + 1][r] = v.y;
        AsT[k4 * 4 + 2][r] = v.z;
        AsT[k4 * 4 + 3][r] = v.w;
    }
#pragma unroll
    for (int q = 0; q < 4; ++q) {
        int idx = tid + 256 * q;
        int j = idx >> 5, k4 = idx & 31;
        float4 v = *(const float4*)(W + j * 128 + k4 * 4);
        WT[k4 * 4 + 0][j] = v.x;
        WT[k4 * 4 + 1][j] = v.y;
        WT[k4 * 4 + 2][j] = v.z;
        WT[k4 * 4 + 3][j] = v.w;
    }
    __syncthreads();
    const int tx = tid & 31, ty = tid >> 5;
    float acc[4] = {0.f, 0.f, 0.f, 0.f};
#pragma unroll 4
    for (int k = 0; k < 128; ++k) {
        float w = WT[k][tx];
        float4 a = *(const float4*)&AsT[k][ty * 4];
        acc[0] += a.x * w;
        acc[1] += a.y * w;
        acc[2] += a.z * w;
        acc[3] += a.w * w;
    }
    float b = bias[tx];
#pragma unroll
    for (int r = 0; r < 4; ++r) {
        int gr = row0 + ty * 4 + r;
        if (gr < N) C[(size_t)gr * 32 + tx] = acc[r] + b;
    }
}

// Fallback (ws too small for CSR): atomic scatter as in R1.
__global__ __launch_bounds__(256) void edge_scatter(
    const int* __restrict__ ei, const float* __restrict__ ew,
    const float* __restrict__ m, float* __restrict__ acc, int E,
    const int* __restrict__ flag) {
    int t = blockIdx.x * 256 + threadIdx.x;
    int e = t >> 5;
    if (e >= E) return;
    int f = (t & 31) << 2;
    int s, d;
    get_edge(ei, e, E, flag[0], s, d);
    float w = ew[e];
    const float4 v = *(const float4*)(m + (size_t)s * 128 + f);
    float* ap = acc + (size_t)d * 128 + f;
    atomicAdd(ap + 0, w * v.x);
    atomicAdd(ap + 1, w * v.y);
    atomicAdd(ap + 2, w * v.z);
    atomicAdd(ap + 3, w * v.w);
}

extern "C" void kernel_launch(void* const* d_in, const int* in_sizes, int n_in,
                              void* d_out, int out_size, void* d_ws, size_t ws_size,
                              hipStream_t stream) {
    const float* x   = (const float*)d_in[0];
    const int* ei    = (const int*)d_in[1];
    const float* ew  = (const float*)d_in[2];
    const float* Wm[3] = {(const float*)d_in[3], (const float*)d_in[6], (const float*)d_in[9]};
    const float* Wu[3] = {(const float*)d_in[4], (const float*)d_in[7], (const float*)d_in[10]};
    const float* bu[3] = {(const float*)d_in[5], (const float*)d_in[8], (const float*)d_in[11]};
    const float* Wout = (const float*)d_in[12];
    const float* bout = (const float*)d_in[13];
    float* out = (float*)d_out;

    const int N = in_sizes[0] / 128;
    const int E = in_sizes[2];

    float* ws   = (float*)d_ws;
    float* mbuf = ws;
    float* acc0 = ws + WS_STRIDE;
    float* acc1 = ws + 2 * WS_STRIDE;
    size_t off  = 3 * WS_STRIDE;
    int* flag   = (int*)(ws + off); off += 1;
    int* deg    = (int*)(ws + off); off += N;
    int* rowptr = (int*)(ws + off); off += N;
    int* csr_src= (int*)(ws + off); off += E;
    float* csr_w= (float*)(ws + off); off += E;
    const bool use_csr = ws_size >= off * sizeof(float);

    detect_idx_kernel<<<1, 256, 0, stream>>>(ei, flag, E);

    const int gG = (N + 63) / 64;
    const int gE1 = (E + 255) / 256;                       // 1 thread/edge
    const int gE32 = (int)(((long long)E * 32 + 255) / 256); // 32 lanes/edge
    const int gO = (N + 31) / 32;
    const int gA = (N * 64 + 255) / 256;                   // wave/node

    if (use_csr) {
        zero_kernel<<<(N + 255) / 256, 256, 0, stream>>>(deg, N);
        hist_kernel<<<gE1, 256, 0, stream>>>(ei, deg, E, flag);
        scan_kernel<<<1, 256, 0, stream>>>(deg, rowptr, N);
        fill_kernel<<<gE1, 256, 0, stream>>>(ei, ew, rowptr, csr_src, csr_w, E, flag);
    }

    const float* hin[4] = {x, acc0, acc1, acc0};
    float* accs[3] = {acc0, acc1, acc0};
    for (int l = 0; l < 3; ++l) {
        if (l == 0) {
            gemm128<false, false><<<gG, 256, 0, stream>>>(hin[l], Wm[l], nullptr, mbuf, N);
            gemm128<false, true><<<gG, 256, 0, stream>>>(hin[l], Wu[l], bu[l], accs[l], N);
        } else {
            gemm128<true, false><<<gG, 256, 0, stream>>>(hin[l], Wm[l], nullptr, mbuf, N);
            gemm128<true, true><<<gG, 256, 0, stream>>>(hin[l], Wu[l], bu[l], accs[l], N);
        }
        if (use_csr) {
            aggregate_kernel<<<gA, 256, 0, stream>>>(csr_src, csr_w, rowptr, deg, mbuf, accs[l], N);
        } else {
            edge_scatter<<<gE32, 256, 0, stream>>>(ei, ew, mbuf, accs[l], E, flag);
        }
    }

    gemm_out<<<gO, 256, 0, stream>>>(acc0, Wout, bout, out, N);
}

// Round 3
// 419.654 us; speedup vs baseline: 10.3300x; 1.6368x over previous
//
#include <hip/hip_runtime.h>
#include <hip/hip_bf16.h>
#include <cstddef>

// ---------------------------------------------------------------------------
// 3-layer MPNN, N=50000, E=800000, D=128, OUT=32.
// R3: bf16 MFMA GEMMs + bf16 message/feature buffers + fast 3-phase scan.
//   layer l: m_bf16 = h@Wm^T ; u_f32 = h@Wu^T+bu ;
//            h'_bf16 = tanh(u + sum_{in-edges} w * m[src])   (tanh in aggregate)
//   out = h3_bf16 @ Wout^T + bout (fp32)
// ---------------------------------------------------------------------------

typedef __attribute__((ext_vector_type(8))) short short8;
typedef __attribute__((ext_vector_type(4))) float f32x4;
typedef unsigned short ushort_t;
typedef unsigned int uint_t;

__device__ inline ushort_t f2bf(float f) {  // round-to-nearest-even
    uint_t u = __float_as_uint(f);
    uint_t r = u + 0x7FFFu + ((u >> 16) & 1u);
    return (ushort_t)(r >> 16);
}
__device__ inline float bf_lo(uint_t u) { return __uint_as_float(u << 16); }
__device__ inline float bf_hi(uint_t u) { return __uint_as_float(u & 0xFFFF0000u); }
__device__ inline uint_t packbf(float a, float b) {
    return (uint_t)f2bf(a) | ((uint_t)f2bf(b) << 16);
}

// flag[0] = 1 -> edge_index stored as int32 [2][E]; 0 -> int64 [2][E].
__global__ void detect_idx_kernel(const int* __restrict__ ei, int* __restrict__ flag, int E) {
    __shared__ int any;
    if (threadIdx.x == 0) any = 0;
    __syncthreads();
    int n = E < 2048 ? E : 2048;
    for (int i = threadIdx.x; i < n; i += 256) {
        if (ei[2 * i + 1] != 0) any = 1;
    }
    __syncthreads();
    if (threadIdx.x == 0) flag[0] = any;
}

__device__ inline void get_edge(const int* __restrict__ ei, int e, int E, int f,
                                int& s, int& d) {
    if (f) {            // int32: [src[E] | dst[E]]
        s = ei[e];
        d = ei[E + e];
    } else {            // int64 little-endian: low words at even offsets
        s = ei[2 * (size_t)e];
        d = ei[2 * ((size_t)E + e)];
    }
}

// ---- weight fp32 -> bf16 conversion (all 7 weights, one launch) ----
struct WPtrs {
    const float* s[7];
    ushort_t* d[7];
    int n[7];
};
__global__ __launch_bounds__(256) void cvt_all(WPtrs p, int total) {
    int i = blockIdx.x * 256 + threadIdx.x;
    if (i >= total) return;
    int w = 0, base = 0;
    while (w < 6 && i >= base + p.n[w]) { base += p.n[w]; ++w; }
    p.d[w][i - base] = f2bf(p.s[w][i - base]);
}

// ---- CSR build ----
__global__ __launch_bounds__(256) void zero_kernel(int* __restrict__ p, int n) {
    int i = blockIdx.x * 256 + threadIdx.x;
    if (i < n) p[i] = 0;
}

__global__ __launch_bounds__(256) void hist_kernel(
    const int* __restrict__ ei, int* __restrict__ deg, int E,
    const int* __restrict__ flag) {
    int e = blockIdx.x * 256 + threadIdx.x;
    if (e >= E) return;
    int s, d;
    get_edge(ei, e, E, flag[0], s, d);
    atomicAdd(&deg[d], 1);
}

// 3-phase exclusive scan of deg[N] -> rowptr[N]
__global__ __launch_bounds__(256) void scan_partial(
    const int* __restrict__ deg, int* __restrict__ bsum, int N) {
    __shared__ int sm[256];
    int i = blockIdx.x * 256 + threadIdx.x;
    sm[threadIdx.x] = i < N ? deg[i] : 0;
    __syncthreads();
    for (int o = 128; o > 0; o >>= 1) {
        if (threadIdx.x < o) sm[threadIdx.x] += sm[threadIdx.x + o];
        __syncthreads();
    }
    if (threadIdx.x == 0) bsum[blockIdx.x] = sm[0];
}
__global__ __launch_bounds__(256) void scan_bsum(
    const int* __restrict__ bsum, int* __restrict__ boff, int PB) {
    __shared__ int sm[256];
    int t = threadIdx.x;
    sm[t] = t < PB ? bsum[t] : 0;
    __syncthreads();
    for (int o = 1; o < 256; o <<= 1) {
        int v = t >= o ? sm[t - o] : 0;
        __syncthreads();
        sm[t] += v;
        __syncthreads();
    }
    if (t < PB) boff[t] = t ? sm[t - 1] : 0;
}
__global__ __launch_bounds__(256) void scan_write(
    const int* __restrict__ deg, const int* __restrict__ boff,
    int* __restrict__ rowptr, int N) {
    __shared__ int sm[256];
    int t = threadIdx.x;
    int i = blockIdx.x * 256 + t;
    int v = i < N ? deg[i] : 0;
    sm[t] = v;
    __syncthreads();
    for (int o = 1; o < 256; o <<= 1) {
        int u = t >= o ? sm[t - o] : 0;
        __syncthreads();
        sm[t] += u;
        __syncthreads();
    }
    if (i < N) rowptr[i] = boff[blockIdx.x] + sm[t] - v;
}

// bucket-fill; mutates rowptr[d] start->end (rowptr becomes rowend)
__global__ __launch_bounds__(256) void fill_kernel(
    const int* __restrict__ ei, const float* __restrict__ ew,
    int* __restrict__ rowptr, int* __restrict__ csr_src,
    float* __restrict__ csr_w, int E, const int* __restrict__ flag) {
    int e = blockIdx.x * 256 + threadIdx.x;
    if (e >= E) return;
    int s, d;
    get_edge(ei, e, E, flag[0], s, d);
    int pos = atomicAdd(&rowptr[d], 1);
    csr_src[pos] = s;
    csr_w[pos] = ew[e];
}

// ---------------------------------------------------------------------------
// MFMA GEMM: C[N,128] = A[N,128] @ W[128,128]^T (+bias). K=128 single shot.
// BM=64, BN=128, 256 threads (4 waves), wave w owns row-tile w, all 8 col-tiles.
// LDS chunk layout: flat[(tile*4 + kstep)*64 + q*16 + m][8 bf16], so both
// staging writes and frag reads are lane-contiguous 16 B (conflict-free).
// Frag layouts per m89/m91: A[m=lane&15][k=(lane>>4)*8+j]; D col=lane&15,
// row=(lane>>4)*4+reg.
// ---------------------------------------------------------------------------
template <bool AF32, bool OUTBF16, bool BIAS>
__global__ __launch_bounds__(256) void mfma_gemm128(
    const void* __restrict__ Aptr, const ushort_t* __restrict__ Wb,
    const float* __restrict__ bias, void* __restrict__ Cptr, int N) {
    __shared__ short As[64 * 128];    // 16 KB
    __shared__ short Ws[128 * 128];   // 32 KB
    const int tid = threadIdx.x;
    const int row0 = blockIdx.x * 64;

    // stage A: 1024 chunks of 8 elements
#pragma unroll
    for (int it = 0; it < 4; ++it) {
        int c = tid + 256 * it;
        int mm = c & 15, q = (c >> 4) & 3, ks = (c >> 6) & 3, rt = c >> 8;
        int gr = row0 + rt * 16 + mm;
        int k0 = ks * 32 + q * 8;
        short8 v = {0, 0, 0, 0, 0, 0, 0, 0};
        if (gr < N) {
            if (AF32) {
                const float* A = (const float*)Aptr;
                float4 x0 = *(const float4*)(A + (size_t)gr * 128 + k0);
                float4 x1 = *(const float4*)(A + (size_t)gr * 128 + k0 + 4);
                v[0] = (short)f2bf(x0.x); v[1] = (short)f2bf(x0.y);
                v[2] = (short)f2bf(x0.z); v[3] = (short)f2bf(x0.w);
                v[4] = (short)f2bf(x1.x); v[5] = (short)f2bf(x1.y);
                v[6] = (short)f2bf(x1.z); v[7] = (short)f2bf(x1.w);
            } else {
                const ushort_t* A = (const ushort_t*)Aptr;
                v = *(const short8*)(A + (size_t)gr * 128 + k0);
            }
        }
        *(short8*)&As[c * 8] = v;
    }
    // stage W: 2048 chunks
#pragma unroll
    for (int it = 0; it < 8; ++it) {
        int c = tid + 256 * it;
        int mm = c & 15, q = (c >> 4) & 3, ks = (c >> 6) & 3, ct = c >> 8;
        *(short8*)&Ws[c * 8] =
            *(const short8*)(Wb + (ct * 16 + mm) * 128 + ks * 32 + q * 8);
    }
    __syncthreads();

    const int wv = tid >> 6, lane = tid & 63;
    const int rt = wv;
    f32x4 acc[8];
#pragma unroll
    for (int ct = 0; ct < 8; ++ct) acc[ct] = (f32x4){0.f, 0.f, 0.f, 0.f};
#pragma unroll
    for (int ks = 0; ks < 4; ++ks) {
        short8 a = *(const short8*)&As[((rt * 4 + ks) * 64 + lane) * 8];
#pragma unroll
        for (int ct = 0; ct < 8; ++ct) {
            short8 b = *(const short8*)&Ws[((ct * 4 + ks) * 64 + lane) * 8];
            acc[ct] = __builtin_amdgcn_mfma_f32_16x16x32_bf16(a, b, acc[ct], 0, 0, 0);
        }
    }
    const int colL = lane & 15, rq = lane >> 4;
#pragma unroll
    for (int ct = 0; ct < 8; ++ct) {
        int col = ct * 16 + colL;
        float bv = BIAS ? bias[col] : 0.f;
#pragma unroll
        for (int reg = 0; reg < 4; ++reg) {
            int gr = row0 + rt * 16 + rq * 4 + reg;
            if (gr >= N) continue;
            float val = acc[ct][reg] + bv;
            if (OUTBF16)
                ((ushort_t*)Cptr)[(size_t)gr * 128 + col] = f2bf(val);
            else
                ((float*)Cptr)[(size_t)gr * 128 + col] = val;
        }
    }
}

// out[N,32] = H_bf16[N,128] @ Wout^T + bout. BM=128, BN=32.
__global__ __launch_bounds__(256) void mfma_gemm_out(
    const ushort_t* __restrict__ H, const ushort_t* __restrict__ Wb,
    const float* __restrict__ bias, float* __restrict__ C, int N) {
    __shared__ short As[128 * 128];  // 32 KB
    __shared__ short Ws[32 * 128];   // 8 KB
    const int tid = threadIdx.x;
    const int row0 = blockIdx.x * 128;
#pragma unroll
    for (int it = 0; it < 8; ++it) {
        int c = tid + 256 * it;
        int mm = c & 15, q = (c >> 4) & 3, ks = (c >> 6) & 3, rt = c >> 8;
        int gr = row0 + rt * 16 + mm;
        short8 v = {0, 0, 0, 0, 0, 0, 0, 0};
        if (gr < N) v = *(const short8*)(H + (size_t)gr * 128 + ks * 32 + q * 8);
        *(short8*)&As[c * 8] = v;
    }
#pragma unroll
    for (int it = 0; it < 2; ++it) {
        int c = tid + 256 * it;
        int mm = c & 15, q = (c >> 4) & 3, ks = (c >> 6) & 3, ct = c >> 8;
        *(short8*)&Ws[c * 8] =
            *(const short8*)(Wb + (ct * 16 + mm) * 128 + ks * 32 + q * 8);
    }
    __syncthreads();
    const int wv = tid >> 6, lane = tid & 63;
    const int rt0 = wv * 2;
    f32x4 acc[2][2];
#pragma unroll
    for (int r = 0; r < 2; ++r)
#pragma unroll
        for (int c = 0; c < 2; ++c) acc[r][c] = (f32x4){0.f, 0.f, 0.f, 0.f};
#pragma unroll
    for (int ks = 0; ks < 4; ++ks) {
        short8 a0 = *(const short8*)&As[(((rt0 + 0) * 4 + ks) * 64 + lane) * 8];
        short8 a1 = *(const short8*)&As[(((rt0 + 1) * 4 + ks) * 64 + lane) * 8];
#pragma unroll
        for (int ct = 0; ct < 2; ++ct) {
            short8 b = *(const short8*)&Ws[((ct * 4 + ks) * 64 + lane) * 8];
            acc[0][ct] = __builtin_amdgcn_mfma_f32_16x16x32_bf16(a0, b, acc[0][ct], 0, 0, 0);
            acc[1][ct] = __builtin_amdgcn_mfma_f32_16x16x32_bf16(a1, b, acc[1][ct], 0, 0, 0);
        }
    }
    const int colL = lane & 15, rq = lane >> 4;
#pragma unroll
    for (int r = 0; r < 2; ++r)
#pragma unroll
        for (int ct = 0; ct < 2; ++ct) {
            int col = ct * 16 + colL;
            float bv = bias[col];
#pragma unroll
            for (int reg = 0; reg < 4; ++reg) {
                int gr = row0 + (rt0 + r) * 16 + rq * 4 + reg;
                if (gr < N) C[(size_t)gr * 32 + col] = acc[r][ct][reg] + bv;
            }
        }
}

// ---------------------------------------------------------------------------
// Aggregate: h'[d] = tanh(u[d] + sum_{in(d)} w * m_bf16[src]).
// 32 lanes per node (2 nodes/wave); lane owns 4 feature cols (uint2 = 4 bf16).
// ---------------------------------------------------------------------------
__global__ __launch_bounds__(256) void aggregate2(
    const int* __restrict__ csr_src, const float* __restrict__ csr_w,
    const int* __restrict__ rowend, const int* __restrict__ deg,
    const ushort_t* __restrict__ m, const float* __restrict__ u,
    ushort_t* __restrict__ h, int N) {
    int t = blockIdx.x * 256 + threadIdx.x;
    int node = t >> 5;
    if (node >= N) return;
    int lane = threadIdx.x & 31;
    int end = rowend[node];
    int beg = end - deg[node];
    float s0 = 0.f, s1 = 0.f, s2 = 0.f, s3 = 0.f;
    int j = beg;
    for (; j + 1 < end; j += 2) {
        int sa = csr_src[j], sb = csr_src[j + 1];
        float wa = csr_w[j], wb = csr_w[j + 1];
        uint2 va = *(const uint2*)(m + (size_t)sa * 128 + lane * 4);
        uint2 vb = *(const uint2*)(m + (size_t)sb * 128 + lane * 4);
        s0 += wa * bf_lo(va.x) + wb * bf_lo(vb.x);
        s1 += wa * bf_hi(va.x) + wb * bf_hi(vb.x);
        s2 += wa * bf_lo(va.y) + wb * bf_lo(vb.y);
        s3 += wa * bf_hi(va.y) + wb * bf_hi(vb.y);
    }
    if (j < end) {
        int sa = csr_src[j];
        float wa = csr_w[j];
        uint2 va = *(const uint2*)(m + (size_t)sa * 128 + lane * 4);
        s0 += wa * bf_lo(va.x);
        s1 += wa * bf_hi(va.x);
        s2 += wa * bf_lo(va.y);
        s3 += wa * bf_hi(va.y);
    }
    const float4 uu = *(const float4*)(u + (size_t)node * 128 + lane * 4);
    float h0 = tanhf(uu.x + s0), h1 = tanhf(uu.y + s1);
    float h2 = tanhf(uu.z + s2), h3 = tanhf(uu.w + s3);
    uint2 outv;
    outv.x = packbf(h0, h1);
    outv.y = packbf(h2, h3);
    *(uint2*)(h + (size_t)node * 128 + lane * 4) = outv;
}

extern "C" void kernel_launch(void* const* d_in, const int* in_sizes, int n_in,
                              void* d_out, int out_size, void* d_ws, size_t ws_size,
                              hipStream_t stream) {
    const float* x   = (const float*)d_in[0];
    const int* ei    = (const int*)d_in[1];
    const float* ew  = (const float*)d_in[2];
    const float* Wm[3] = {(const float*)d_in[3], (const float*)d_in[6], (const float*)d_in[9]};
    const float* Wu[3] = {(const float*)d_in[4], (const float*)d_in[7], (const float*)d_in[10]};
    const float* bu[3] = {(const float*)d_in[5], (const float*)d_in[8], (const float*)d_in[11]};
    const float* Wout = (const float*)d_in[12];
    const float* bout = (const float*)d_in[13];
    float* out = (float*)d_out;

    const int N = in_sizes[0] / 128;
    const int E = in_sizes[2];
    const size_t NPAD = 50048;

    // workspace carve-up
    ushort_t* mbuf = (ushort_t*)d_ws;             // [N,128] bf16
    ushort_t* hbuf = mbuf + NPAD * 128;           // [N,128] bf16
    float* ubuf    = (float*)(hbuf + NPAD * 128); // [N,128] fp32
    ushort_t* wbuf = (ushort_t*)(ubuf + NPAD * 128);  // 7 x 16384 bf16
    int* flag      = (int*)(wbuf + 7 * 16384);
    int* deg       = flag + 1;
    int* rowptr    = deg + N;
    int* bsum      = rowptr + N;
    int* boff      = bsum + 256;
    int* csr_src   = boff + 256;
    float* csr_w   = (float*)(csr_src + E);
    (void)ws_size;

    ushort_t* wb[7];
    for (int i = 0; i < 7; ++i) wb[i] = wbuf + i * 16384;

    detect_idx_kernel<<<1, 256, 0, stream>>>(ei, flag, E);

    // weight conversion (one launch)
    WPtrs wp;
    wp.s[0] = Wm[0]; wp.s[1] = Wu[0]; wp.s[2] = Wm[1]; wp.s[3] = Wu[1];
    wp.s[4] = Wm[2]; wp.s[5] = Wu[2]; wp.s[6] = Wout;
    for (int i = 0; i < 7; ++i) wp.d[i] = wb[i];
    for (int i = 0; i < 6; ++i) wp.n[i] = 16384;
    wp.n[6] = 4096;
    int wtotal = 6 * 16384 + 4096;
    cvt_all<<<(wtotal + 255) / 256, 256, 0, stream>>>(wp, wtotal);

    // CSR build
    const int PB = (N + 255) / 256;   // 196
    const int gE1 = (E + 255) / 256;  // 3125
    zero_kernel<<<PB, 256, 0, stream>>>(deg, N);
    hist_kernel<<<gE1, 256, 0, stream>>>(ei, deg, E, flag);
    scan_partial<<<PB, 256, 0, stream>>>(deg, bsum, N);
    scan_bsum<<<1, 256, 0, stream>>>(bsum, boff, PB);
    scan_write<<<PB, 256, 0, stream>>>(deg, boff, rowptr, N);
    fill_kernel<<<gE1, 256, 0, stream>>>(ei, ew, rowptr, csr_src, csr_w, E, flag);

    const int gG = (N + 63) / 64;     // 782
    const int gA = (int)(((long long)N * 32 + 255) / 256);  // 6250
    const int gO = (N + 127) / 128;   // 391

    // Layer 0 (A = x fp32)
    mfma_gemm128<true, true, false><<<gG, 256, 0, stream>>>(x, wb[0], nullptr, mbuf, N);
    mfma_gemm128<true, false, true><<<gG, 256, 0, stream>>>(x, wb[1], bu[0], ubuf, N);
    aggregate2<<<gA, 256, 0, stream>>>(csr_src, csr_w, rowptr, deg, mbuf, ubuf, hbuf, N);
    // Layers 1,2 (A = hbuf bf16)
    for (int l = 1; l < 3; ++l) {
        mfma_gemm128<false, true, false><<<gG, 256, 0, stream>>>(hbuf, wb[2 * l], nullptr, mbuf, N);
        mfma_gemm128<false, false, true><<<gG, 256, 0, stream>>>(hbuf, wb[2 * l + 1], bu[l], ubuf, N);
        aggregate2<<<gA, 256, 0, stream>>>(csr_src, csr_w, rowptr, deg, mbuf, ubuf, hbuf, N);
    }
    // Output projection
    mfma_gemm_out<<<gO, 256, 0, stream>>>(hbuf, wb[6], bout, out, N);
}

// Round 4
// 400.517 us; speedup vs baseline: 10.8236x; 1.0478x over previous
//
#include <hip/hip_runtime.h>
#include <hip/hip_bf16.h>
#include <cstddef>

// ---------------------------------------------------------------------------
// 3-layer MPNN, N=50000, E=800000, D=128, OUT=32.
// R4: use linearity  sum_e w_e*(h[src]@Wm^T) = (sum_e w_e*h[src])@Wm^T.
//   per layer: g = Sigma_in-edges w * h[src]   (gather, bf16 out)
//              h' = tanh([g|h] @ [Wm;Wu]^T + bu)   (K=256 MFMA GEMM, tanh epi)
// Eliminates the m buffer and the u buffer entirely.
// CSR entry packed as int2 (src, w bits) -> one 8B scattered write per edge.
// ---------------------------------------------------------------------------

typedef __attribute__((ext_vector_type(8))) short short8;
typedef __attribute__((ext_vector_type(4))) float f32x4;
typedef unsigned short ushort_t;
typedef unsigned int uint_t;

__device__ inline ushort_t f2bf(float f) {  // round-to-nearest-even
    uint_t u = __float_as_uint(f);
    uint_t r = u + 0x7FFFu + ((u >> 16) & 1u);
    return (ushort_t)(r >> 16);
}
__device__ inline float bf_lo(uint_t u) { return __uint_as_float(u << 16); }
__device__ inline float bf_hi(uint_t u) { return __uint_as_float(u & 0xFFFF0000u); }
__device__ inline uint_t packbf(float a, float b) {
    return (uint_t)f2bf(a) | ((uint_t)f2bf(b) << 16);
}

__device__ inline void get_edge(const int* __restrict__ ei, int e, int E, int f,
                                int& s, int& d) {
    if (f) {            // int32: [src[E] | dst[E]]
        s = ei[e];
        d = ei[E + e];
    } else {            // int64 little-endian: low words at even offsets
        s = ei[2 * (size_t)e];
        d = ei[2 * ((size_t)E + e)];
    }
}

// ---------------------------------------------------------------------------
// Fused setup: zero deg | detect idx layout | build bf16 Wcat=[Wm|Wu] + Wout |
// convert x -> bf16. One launch, block ranges.
// ---------------------------------------------------------------------------
struct SetupArgs {
    const float* Wm0; const float* Wu0;
    const float* Wm1; const float* Wu1;
    const float* Wm2; const float* Wu2;
    const float* Wout;
    const float* x; const int* ei;
    ushort_t* wcat;    // 3 * 128*256
    ushort_t* woutb;   // 32*128
    ushort_t* xb;      // N*128
    int* deg; int* flag;
    int N, E;
    int ZB, WB, XB;    // block counts per phase
};
__global__ __launch_bounds__(256) void setup_kernel(SetupArgs a) {
    int bx = blockIdx.x, t = threadIdx.x;
    if (bx < a.ZB) {                       // zero deg
        int i = bx * 256 + t;
        if (i < a.N) a.deg[i] = 0;
        return;
    }
    bx -= a.ZB;
    if (bx == 0) {                         // detect int32 vs int64
        __shared__ int any;
        if (t == 0) any = 0;
        __syncthreads();
        int n = a.E < 2048 ? a.E : 2048;
        for (int i = t; i < n; i += 256)
            if (a.ei[2 * i + 1] != 0) any = 1;
        __syncthreads();
        if (t == 0) a.flag[0] = any;
        return;
    }
    bx -= 1;
    if (bx < a.WB) {                       // weight convert + concat
        int i = bx * 256 + t;
        if (i < 3 * 32768) {
            int l = i >> 15, rem = i & 32767, r = rem >> 8, k = rem & 255;
            const float* Wm = l == 0 ? a.Wm0 : (l == 1 ? a.Wm1 : a.Wm2);
            const float* Wu = l == 0 ? a.Wu0 : (l == 1 ? a.Wu1 : a.Wu2);
            float v = k < 128 ? Wm[r * 128 + k] : Wu[r * 128 + (k - 128)];
            a.wcat[(size_t)l * 32768 + r * 256 + k] = f2bf(v);
        } else if (i < 3 * 32768 + 4096) {
            int j = i - 3 * 32768;
            a.woutb[j] = f2bf(a.Wout[j]);
        }
        return;
    }
    bx -= a.WB;
    {                                      // x fp32 -> bf16, 4 elems/thread
        int j = bx * 256 + t;
        if (j < a.N * 32) {
            float4 v = *(const float4*)(a.x + (size_t)j * 4);
            uint2 o;
            o.x = packbf(v.x, v.y);
            o.y = packbf(v.z, v.w);
            *(uint2*)(a.xb + (size_t)j * 4) = o;
        }
    }
}

// ---- CSR build ----
__global__ __launch_bounds__(256) void hist_kernel(
    const int* __restrict__ ei, int* __restrict__ deg, int E,
    const int* __restrict__ flag) {
    int e = blockIdx.x * 256 + threadIdx.x;
    if (e >= E) return;
    int s, d;
    get_edge(ei, e, E, flag[0], s, d);
    atomicAdd(&deg[d], 1);
}

__global__ __launch_bounds__(256) void scan_partial(
    const int* __restrict__ deg, int* __restrict__ bsum, int N) {
    __shared__ int sm[256];
    int i = blockIdx.x * 256 + threadIdx.x;
    sm[threadIdx.x] = i < N ? deg[i] : 0;
    __syncthreads();
    for (int o = 128; o > 0; o >>= 1) {
        if (threadIdx.x < o) sm[threadIdx.x] += sm[threadIdx.x + o];
        __syncthreads();
    }
    if (threadIdx.x == 0) bsum[blockIdx.x] = sm[0];
}
__global__ __launch_bounds__(256) void scan_bsum(
    const int* __restrict__ bsum, int* __restrict__ boff, int PB) {
    __shared__ int sm[256];
    int t = threadIdx.x;
    sm[t] = t < PB ? bsum[t] : 0;
    __syncthreads();
    for (int o = 1; o < 256; o <<= 1) {
        int v = t >= o ? sm[t - o] : 0;
        __syncthreads();
        sm[t] += v;
        __syncthreads();
    }
    if (t < PB) boff[t] = t ? sm[t - 1] : 0;
}
__global__ __launch_bounds__(256) void scan_write(
    const int* __restrict__ deg, const int* __restrict__ boff,
    int* __restrict__ rowptr, int N) {
    __shared__ int sm[256];
    int t = threadIdx.x;
    int i = blockIdx.x * 256 + t;
    int v = i < N ? deg[i] : 0;
    sm[t] = v;
    __syncthreads();
    for (int o = 1; o < 256; o <<= 1) {
        int u = t >= o ? sm[t - o] : 0;
        __syncthreads();
        sm[t] += u;
        __syncthreads();
    }
    if (i < N) rowptr[i] = boff[blockIdx.x] + sm[t] - v;
}

// bucket-fill; one packed 8B scattered write per edge. rowptr -> rowend.
__global__ __launch_bounds__(256) void fill_kernel(
    const int* __restrict__ ei, const float* __restrict__ ew,
    int* __restrict__ rowptr, int2* __restrict__ csr_sw, int E,
    const int* __restrict__ flag) {
    int e = blockIdx.x * 256 + threadIdx.x;
    if (e >= E) return;
    int s, d;
    get_edge(ei, e, E, flag[0], s, d);
    int pos = atomicAdd(&rowptr[d], 1);
    int2 v;
    v.x = s;
    v.y = __float_as_int(ew[e]);
    csr_sw[pos] = v;
}

// ---------------------------------------------------------------------------
// Aggregate h: g[d] = Sigma_{in(d)} w * h[src]  (bf16 in, fp32 acc, bf16 out)
// 32 lanes per node; lane owns 4 feature cols (uint2 = 4 bf16).
// ---------------------------------------------------------------------------
__global__ __launch_bounds__(256) void aggregate_g(
    const int2* __restrict__ csr_sw, const int* __restrict__ rowend,
    const int* __restrict__ deg, const ushort_t* __restrict__ h,
    ushort_t* __restrict__ g, int N) {
    int t = blockIdx.x * 256 + threadIdx.x;
    int node = t >> 5;
    if (node >= N) return;
    int lane = threadIdx.x & 31;
    int end = rowend[node];
    int beg = end - deg[node];
    float s0 = 0.f, s1 = 0.f, s2 = 0.f, s3 = 0.f;
    int j = beg;
    for (; j + 1 < end; j += 2) {
        int2 ea = csr_sw[j], eb = csr_sw[j + 1];
        float wa = __int_as_float(ea.y), wb = __int_as_float(eb.y);
        uint2 va = *(const uint2*)(h + (size_t)ea.x * 128 + lane * 4);
        uint2 vb = *(const uint2*)(h + (size_t)eb.x * 128 + lane * 4);
        s0 += wa * bf_lo(va.x) + wb * bf_lo(vb.x);
        s1 += wa * bf_hi(va.x) + wb * bf_hi(vb.x);
        s2 += wa * bf_lo(va.y) + wb * bf_lo(vb.y);
        s3 += wa * bf_hi(va.y) + wb * bf_hi(vb.y);
    }
    if (j < end) {
        int2 ea = csr_sw[j];
        float wa = __int_as_float(ea.y);
        uint2 va = *(const uint2*)(h + (size_t)ea.x * 128 + lane * 4);
        s0 += wa * bf_lo(va.x);
        s1 += wa * bf_hi(va.x);
        s2 += wa * bf_lo(va.y);
        s3 += wa * bf_hi(va.y);
    }
    uint2 o;
    o.x = packbf(s0, s1);
    o.y = packbf(s2, s3);
    *(uint2*)(g + (size_t)node * 128 + lane * 4) = o;
}

// ---------------------------------------------------------------------------
// Fused layer GEMM: Hout[N,128] = tanh([G|H][N,256] @ Wcat[128,256]^T + bu)
// BM=64, BN=128, K split in two 128-chunks (chunk0 A=G, chunk1 A=H).
// LDS chunk layout as R3 (lane-contiguous 16B, conflict-free).
// ---------------------------------------------------------------------------
__global__ __launch_bounds__(256) void fused_gemm(
    const ushort_t* __restrict__ G, const ushort_t* __restrict__ H,
    const ushort_t* __restrict__ Wcat, const float* __restrict__ bias,
    ushort_t* __restrict__ Hout, int N) {
    __shared__ short As[64 * 128];    // 16 KB
    __shared__ short Ws[128 * 128];   // 32 KB
    const int tid = threadIdx.x;
    const int row0 = blockIdx.x * 64;
    const int wv = tid >> 6, lane = tid & 63;
    const int rt = wv;

    f32x4 acc[8];
#pragma unroll
    for (int ct = 0; ct < 8; ++ct) acc[ct] = (f32x4){0.f, 0.f, 0.f, 0.f};

#pragma unroll
    for (int chunk = 0; chunk < 2; ++chunk) {
        const ushort_t* A = chunk ? H : G;
        const int kco = chunk * 128;
        if (chunk) __syncthreads();  // protect LDS reuse
        // stage A: 1024 chunks of 8 bf16
#pragma unroll
        for (int it = 0; it < 4; ++it) {
            int c = tid + 256 * it;
            int mm = c & 15, q = (c >> 4) & 3, ks = (c >> 6) & 3, rtile = c >> 8;
            int gr = row0 + rtile * 16 + mm;
            short8 v = {0, 0, 0, 0, 0, 0, 0, 0};
            if (gr < N) v = *(const short8*)(A + (size_t)gr * 128 + ks * 32 + q * 8);
            *(short8*)&As[c * 8] = v;
        }
        // stage W: 2048 chunks
#pragma unroll
        for (int it = 0; it < 8; ++it) {
            int c = tid + 256 * it;
            int mm = c & 15, q = (c >> 4) & 3, ks = (c >> 6) & 3, ct = c >> 8;
            *(short8*)&Ws[c * 8] =
                *(const short8*)(Wcat + (size_t)(ct * 16 + mm) * 256 + kco + ks * 32 + q * 8);
        }
        __syncthreads();
#pragma unroll
        for (int ks = 0; ks < 4; ++ks) {
            short8 a = *(const short8*)&As[((rt * 4 + ks) * 64 + lane) * 8];
#pragma unroll
            for (int ct = 0; ct < 8; ++ct) {
                short8 b = *(const short8*)&Ws[((ct * 4 + ks) * 64 + lane) * 8];
                acc[ct] = __builtin_amdgcn_mfma_f32_16x16x32_bf16(a, b, acc[ct], 0, 0, 0);
            }
        }
    }
    const int colL = lane & 15, rq = lane >> 4;
#pragma unroll
    for (int ct = 0; ct < 8; ++ct) {
        int col = ct * 16 + colL;
        float bv = bias[col];
#pragma unroll
        for (int reg = 0; reg < 4; ++reg) {
            int gr = row0 + rt * 16 + rq * 4 + reg;
            if (gr >= N) continue;
            Hout[(size_t)gr * 128 + col] = f2bf(tanhf(acc[ct][reg] + bv));
        }
    }
}

// out[N,32] = H_bf16[N,128] @ Wout^T + bout (fp32 out). BM=128.
__global__ __launch_bounds__(256) void mfma_gemm_out(
    const ushort_t* __restrict__ H, const ushort_t* __restrict__ Wb,
    const float* __restrict__ bias, float* __restrict__ C, int N) {
    __shared__ short As[128 * 128];  // 32 KB
    __shared__ short Ws[32 * 128];   // 8 KB
    const int tid = threadIdx.x;
    const int row0 = blockIdx.x * 128;
#pragma unroll
    for (int it = 0; it < 8; ++it) {
        int c = tid + 256 * it;
        int mm = c & 15, q = (c >> 4) & 3, ks = (c >> 6) & 3, rt = c >> 8;
        int gr = row0 + rt * 16 + mm;
        short8 v = {0, 0, 0, 0, 0, 0, 0, 0};
        if (gr < N) v = *(const short8*)(H + (size_t)gr * 128 + ks * 32 + q * 8);
        *(short8*)&As[c * 8] = v;
    }
#pragma unroll
    for (int it = 0; it < 2; ++it) {
        int c = tid + 256 * it;
        int mm = c & 15, q = (c >> 4) & 3, ks = (c >> 6) & 3, ct = c >> 8;
        *(short8*)&Ws[c * 8] =
            *(const short8*)(Wb + (ct * 16 + mm) * 128 + ks * 32 + q * 8);
    }
    __syncthreads();
    const int wv = tid >> 6, lane = tid & 63;
    const int rt0 = wv * 2;
    f32x4 acc[2][2];
#pragma unroll
    for (int r = 0; r < 2; ++r)
#pragma unroll
        for (int c = 0; c < 2; ++c) acc[r][c] = (f32x4){0.f, 0.f, 0.f, 0.f};
#pragma unroll
    for (int ks = 0; ks < 4; ++ks) {
        short8 a0 = *(const short8*)&As[(((rt0 + 0) * 4 + ks) * 64 + lane) * 8];
        short8 a1 = *(const short8*)&As[(((rt0 + 1) * 4 + ks) * 64 + lane) * 8];
#pragma unroll
        for (int ct = 0; ct < 2; ++ct) {
            short8 b = *(const short8*)&Ws[((ct * 4 + ks) * 64 + lane) * 8];
            acc[0][ct] = __builtin_amdgcn_mfma_f32_16x16x32_bf16(a0, b, acc[0][ct], 0, 0, 0);
            acc[1][ct] = __builtin_amdgcn_mfma_f32_16x16x32_bf16(a1, b, acc[1][ct], 0, 0, 0);
        }
    }
    const int colL = lane & 15, rq = lane >> 4;
#pragma unroll
    for (int r = 0; r < 2; ++r)
#pragma unroll
        for (int ct = 0; ct < 2; ++ct) {
            int col = ct * 16 + colL;
            float bv = bias[col];
#pragma unroll
            for (int reg = 0; reg < 4; ++reg) {
                int gr = row0 + (rt0 + r) * 16 + rq * 4 + reg;
                if (gr < N) C[(size_t)gr * 32 + col] = acc[r][ct][reg] + bv;
            }
        }
}

extern "C" void kernel_launch(void* const* d_in, const int* in_sizes, int n_in,
                              void* d_out, int out_size, void* d_ws, size_t ws_size,
                              hipStream_t stream) {
    const float* x   = (const float*)d_in[0];
    const int* ei    = (const int*)d_in[1];
    const float* ew  = (const float*)d_in[2];
    const float* Wm[3] = {(const float*)d_in[3], (const float*)d_in[6], (const float*)d_in[9]};
    const float* Wu[3] = {(const float*)d_in[4], (const float*)d_in[7], (const float*)d_in[10]};
    const float* bu[3] = {(const float*)d_in[5], (const float*)d_in[8], (const float*)d_in[11]};
    const float* Wout = (const float*)d_in[12];
    const float* bout = (const float*)d_in[13];
    float* out = (float*)d_out;

    const int N = in_sizes[0] / 128;
    const int E = in_sizes[2];
    const size_t NPAD = 50048;

    // workspace carve-up (bf16 buffers first, then ints, then int2 csr)
    ushort_t* xb   = (ushort_t*)d_ws;               // [N,128] bf16
    ushort_t* hA   = xb + NPAD * 128;
    ushort_t* hB   = hA + NPAD * 128;
    ushort_t* gbuf = hB + NPAD * 128;
    ushort_t* wcat = gbuf + NPAD * 128;             // 3*128*256 bf16
    ushort_t* woutb = wcat + 3 * 32768;             // 32*128 bf16
    int* flag      = (int*)(woutb + 4096);
    int* deg       = flag + 1;
    int* rowptr    = deg + N;
    int* bsum      = rowptr + N;
    int* boff      = bsum + 256;
    int* pad       = boff + 256;                    // keep int2 8B-aligned
    int2* csr_sw   = (int2*)(((uintptr_t)(pad) + 7) & ~(uintptr_t)7);
    (void)ws_size;

    const int ZB = (N + 255) / 256;        // 196
    const int WB = (3 * 32768 + 4096 + 255) / 256;  // 400
    const int XB = (N * 32 + 255) / 256;   // 6250
    const int PB = ZB;
    const int gE1 = (E + 255) / 256;       // 3125
    const int gG = (N + 63) / 64;          // 782
    const int gA = (int)(((long long)N * 32 + 255) / 256);  // 6250
    const int gO = (N + 127) / 128;        // 391

    SetupArgs sa;
    sa.Wm0 = Wm[0]; sa.Wu0 = Wu[0];
    sa.Wm1 = Wm[1]; sa.Wu1 = Wu[1];
    sa.Wm2 = Wm[2]; sa.Wu2 = Wu[2];
    sa.Wout = Wout; sa.x = x; sa.ei = ei;
    sa.wcat = wcat; sa.woutb = woutb; sa.xb = xb;
    sa.deg = deg; sa.flag = flag;
    sa.N = N; sa.E = E; sa.ZB = ZB; sa.WB = WB; sa.XB = XB;
    setup_kernel<<<ZB + 1 + WB + XB, 256, 0, stream>>>(sa);

    hist_kernel<<<gE1, 256, 0, stream>>>(ei, deg, E, flag);
    scan_partial<<<PB, 256, 0, stream>>>(deg, bsum, N);
    scan_bsum<<<1, 256, 0, stream>>>(bsum, boff, PB);
    scan_write<<<PB, 256, 0, stream>>>(deg, boff, rowptr, N);
    fill_kernel<<<gE1, 256, 0, stream>>>(ei, ew, rowptr, csr_sw, E, flag);

    // layer 0: h=xb -> hA ; layer 1: hA -> hB ; layer 2: hB -> hA
    const ushort_t* hin[3] = {xb, hA, hB};
    ushort_t* hout[3] = {hA, hB, hA};
    for (int l = 0; l < 3; ++l) {
        aggregate_g<<<gA, 256, 0, stream>>>(csr_sw, rowptr, deg, hin[l], gbuf, N);
        fused_gemm<<<gG, 256, 0, stream>>>(gbuf, hin[l], wcat + (size_t)l * 32768,
                                           bu[l], hout[l], N);
    }
    mfma_gemm_out<<<gO, 256, 0, stream>>>(hA, woutb, bout, out, N);
}